// Round 10
// baseline (214.351 us; speedup 1.0000x reference)
//
#include <hip/hip_runtime.h>
#include <hip/hip_fp16.h>

#define Nn 50000
#define Ee 800000
#define D  128
#define SLOT 64

typedef _Float16 f16x8 __attribute__((ext_vector_type(8)));
typedef _Float16 h2    __attribute__((ext_vector_type(2)));
typedef float    f32x4 __attribute__((ext_vector_type(4)));

// node blob: 256 halfs per node = [sem16 row (128) | y16 row (128)] = 512 B

// ---------------- K0: zero cnt + convert W -> fp16 (once) --------------------
// bids 0..49: zero 51,200 ints. bids 50..65: convert 4096 float4 -> w16.
__global__ __launch_bounds__(256) void k_init(const float* __restrict__ W,
                                              int* __restrict__ cnt,
                                              __half* __restrict__ w16) {
  int bid = blockIdx.x, tid = threadIdx.x;
  if (bid < 50) {
    int i = bid * 256 + tid;
    *(int4*)(cnt + i * 4) = (int4){0, 0, 0, 0};
  } else {
    int i = (bid - 50) * 256 + tid;        // 0..4095, one float4 each
    float4 w = *(const float4*)(W + (size_t)i * 4);
    __half2* dst = (__half2*)(w16 + (size_t)i * 4);
    dst[0] = __floats2half2_rn(w.x, w.y);
    dst[1] = __floats2half2_rn(w.z, w.w);
  }
}

// ---------------- K1 phase A: scatter (even bid) | gemm+norm (odd bid) -------
// ZERO LDS -> 8 blocks/CU; every CU co-hosts ~4 scatter + ~4 gemm/norm blocks.
// gemm reads W16 from global (32 KB, L1/L2-resident, broadcast across waves).
__global__ __launch_bounds__(256) void k_phaseA(const float* __restrict__ x,
                                                const __half* __restrict__ w16,
                                                const float* __restrict__ b,
                                                const int* __restrict__ ei,
                                                const float* __restrict__ sem,
                                                __half* __restrict__ blob,
                                                int* __restrict__ cnt,
                                                unsigned short* __restrict__ slot16) {
  int bid = blockIdx.x, tid = threadIdx.x;

  if ((bid & 1) == 0) {
    // ---- scatter role: 512 edges/block, 2 independent chains/thread ----
    int base = (bid >> 1) * 512 + tid;
#pragma unroll
    for (int u = 0; u < 2; u++) {
      int e = base + u * 256;
      if (e < Ee) {
        int s = ei[e], d = ei[Ee + e];
        int pos = atomicAdd(cnt + d, 1);
        if (pos < SLOT)                    // Poisson(16): P(deg>64) ~ 2e-18
          slot16[(size_t)d * SLOT + pos] = (unsigned short)s;
      }
    }
    return;
  }

  // ---- gemm+norm role: 32 nodes/block ----
  int nb = bid >> 1;                       // 0..1562, covers 50,016 >= Nn
  int n0 = nb * 32;
  int wave = tid >> 6, lane = tid & 63;

  // norm: each wave normalizes 8 nodes (lane = 2 dims, shfl reduce)
#pragma unroll
  for (int it = 0; it < 8; it++) {
    int n = n0 + it * 4 + wave;
    if (n < Nn) {
      const float2 v = *(const float2*)(sem + (size_t)n * D + 2 * lane);
      float p = v.x * v.x + v.y * v.y;
#pragma unroll
      for (int off = 32; off > 0; off >>= 1) p += __shfl_xor(p, off);
      float inv = 1.0f / fmaxf(sqrtf(p), 1e-8f);
      *(__half2*)(blob + (size_t)n * 256 + 2 * lane) = __floats2half2_rn(v.x * inv, v.y * inv);
    }
  }

  // gemm: 32 rows, waves col-split: rs = row strip, ch = col half
  int rs = (wave >> 1) * 16;           // 0 / 16
  int ch = (wave & 1) * 64;            // 0 / 64
  int g = lane >> 4, n16 = lane & 15;

  int arow = n0 + rs + n16; if (arow >= Nn) arow = Nn - 1;
  const float* xr = x + (size_t)arow * 128 + g * 8;
  union { f16x8 v; __half2 h[4]; } af[4];
#pragma unroll
  for (int kt = 0; kt < 4; kt++) {
    float4 u0 = *(const float4*)(xr + kt * 32);
    float4 u1 = *(const float4*)(xr + kt * 32 + 4);
    af[kt].h[0] = __floats2half2_rn(u0.x, u0.y);
    af[kt].h[1] = __floats2half2_rn(u0.z, u0.w);
    af[kt].h[2] = __floats2half2_rn(u1.x, u1.y);
    af[kt].h[3] = __floats2half2_rn(u1.z, u1.w);
  }

  f32x4 acc[4];
#pragma unroll
  for (int jt = 0; jt < 4; jt++) {
    float bias = b[ch + jt * 16 + n16];
    acc[jt] = (f32x4){bias, bias, bias, bias};
  }
#pragma unroll
  for (int kt = 0; kt < 4; kt++) {
#pragma unroll
    for (int jt = 0; jt < 4; jt++) {
      f16x8 bf = *(const f16x8*)(w16 + (size_t)(ch + jt * 16 + n16) * 128 + kt * 32 + g * 8);
      acc[jt] = __builtin_amdgcn_mfma_f32_16x16x32_f16(af[kt].v, bf, acc[jt], 0, 0, 0);
    }
  }
  // C/D: col = lane&15 (-> out col ch+jt*16+n16), row = g*4 + reg
#pragma unroll
  for (int jt = 0; jt < 4; jt++) {
#pragma unroll
    for (int rr = 0; rr < 4; rr++) {
      int row = n0 + rs + g * 4 + rr;
      if (row < Nn)
        blob[(size_t)row * 256 + 128 + ch + jt * 16 + n16] = __float2half(acc[jt][rr]);
    }
  }
}

// ---------------- K2: fused gather, software-prefetched (single launch) ------
__global__ __launch_bounds__(256) void k_fused(const __half* __restrict__ blob,
                                               const unsigned short* __restrict__ slot16,
                                               const int* __restrict__ cnt,
                                               float* __restrict__ out) {
  int d = (blockIdx.x * 256 + threadIdx.x) >> 6;
  int lane = threadIdx.x & 63;
  int g = lane >> 4, l16 = lane & 15;
  int c = cnt[d]; if (c > SLOT) c = SLOT;

  int sv = (lane < c) ? (int)slot16[(size_t)d * SLOT + lane] : 0;

  f16x8 dh = *(const f16x8*)(blob + (size_t)d * 256 + l16 * 8);

  float o[8] = {0, 0, 0, 0, 0, 0, 0, 0};
  float Sp = 0.0f;

  f16x8 rs0, ry0;
  if (c > 0) {                             // preload edge block i=0
    int ce = (g < c) ? g : c - 1;
    int sa = __shfl(sv, ce);
    const __half* nbp = blob + (size_t)sa * 256;
    rs0 = *(const f16x8*)(nbp + l16 * 8);
    ry0 = *(const f16x8*)(nbp + 128 + l16 * 8);
  }

  for (int i = 0; i < c; i += 4) {
    f16x8 rs = rs0, ry = ry0;
    // prefetch next edge block BEFORE the reduce/exp dependency chain
    if (i + 4 < c) {
      int e2 = i + 4 + g;
      int ce2 = (e2 < c) ? e2 : c - 1;
      int sa2 = __shfl(sv, ce2);
      const __half* nb2 = blob + (size_t)sa2 * 256;
      rs0 = *(const f16x8*)(nb2 + l16 * 8);
      ry0 = *(const f16x8*)(nb2 + 128 + l16 * 8);
    }
    float p = __builtin_amdgcn_fdot2((h2){rs[0], rs[1]}, (h2){dh[0], dh[1]}, 0.0f, false);
    p = __builtin_amdgcn_fdot2((h2){rs[2], rs[3]}, (h2){dh[2], dh[3]}, p, false);
    p = __builtin_amdgcn_fdot2((h2){rs[4], rs[5]}, (h2){dh[4], dh[5]}, p, false);
    p = __builtin_amdgcn_fdot2((h2){rs[6], rs[7]}, (h2){dh[6], dh[7]}, p, false);
    p += __shfl_xor(p, 1); p += __shfl_xor(p, 2);
    p += __shfl_xor(p, 4); p += __shfl_xor(p, 8);
    float ew = __expf(p); if (i + g >= c) ew = 0.0f;
    Sp += ew;
#pragma unroll
    for (int k = 0; k < 8; k++) o[k] += ew * (float)ry[k];
  }

#pragma unroll
  for (int k = 0; k < 8; k++) {
    o[k] += __shfl_xor(o[k], 16);
    o[k] += __shfl_xor(o[k], 32);
  }
  Sp += __shfl_xor(Sp, 16);
  Sp += __shfl_xor(Sp, 32);

  if (g == 0) {
    float inv = 1.0f / (Sp + 1e-16f);
    float4 r0; r0.x = o[0] * inv; r0.y = o[1] * inv; r0.z = o[2] * inv; r0.w = o[3] * inv;
    float4 r1; r1.x = o[4] * inv; r1.y = o[5] * inv; r1.z = o[6] * inv; r1.w = o[7] * inv;
    float* op = out + (size_t)d * D + l16 * 8;
    *(float4*)op = r0;
    *(float4*)(op + 4) = r1;
  }
}

// ---------------- launch ----------------
extern "C" void kernel_launch(void* const* d_in, const int* in_sizes, int n_in,
                              void* d_out, int out_size, void* d_ws, size_t ws_size,
                              hipStream_t stream) {
  const float* x     = (const float*)d_in[0];
  const int*   ei    = (const int*)d_in[1];    // int32 per harness contract
  const float* sem   = (const float*)d_in[2];
  const float* W_src = (const float*)d_in[3];
  const float* b_src = (const float*)d_in[4];
  float* out = (float*)d_out;

  char* ws = (char*)d_ws;
  const size_t O_BLOB = 0;          // N*256*2 = 25,600,000 (sem|y interleaved)
  const size_t O_CNT  = 25600000;   // 51,200-int padded region
  const size_t O_SS   = 25804800;   // N*64*2  =  6,400,000 (uint16 slots)
  const size_t O_W16  = 32204800;   // 128*128*2 = 32,768 (fp16 W)
  const size_t NEED   = 32237568;
  if (ws_size < NEED) return;

  __half* blob = (__half*)(ws + O_BLOB);
  int* cnt = (int*)(ws + O_CNT);
  unsigned short* slot16 = (unsigned short*)(ws + O_SS);
  __half* w16 = (__half*)(ws + O_W16);

  k_init<<<66, 256, 0, stream>>>(W_src, cnt, w16);
  k_phaseA<<<3126, 256, 0, stream>>>(x, w16, b_src, ei, sem, blob, cnt, slot16);
  k_fused<<<12500, 256, 0, stream>>>(blob, slot16, cnt, out);
}